// Round 4
// baseline (17464.165 us; speedup 1.0000x reference)
//
#include <hip/hip_runtime.h>
#include <float.h>
#include <math.h>

#define DIM 2048
#define HEADS 16
#define BATCH 2
#define SEQ 2048
#define HD 128              // head dim
#define MROWS (BATCH * SEQ) // 4096

// ---------------------------------------------------------------------------
// fp32 tiled GEMM: C(MxN) = A(MxK) @ B(KxN), all row-major, dims % 128 == 0.
// 128x128 tile, BK=16, 256 threads, 8x8 micro-tile per thread. (unchanged)
// ---------------------------------------------------------------------------
__global__ __launch_bounds__(256) void gemm_f32(const float* __restrict__ A,
                                                const float* __restrict__ B,
                                                float* __restrict__ C,
                                                int M, int N, int K) {
    constexpr int GM = 128, GN = 128, GK = 16;
    __shared__ float As[GK][GM + 4];
    __shared__ float Bs[GK][GN];

    const int t = threadIdx.x;
    const int bm = blockIdx.y * GM;
    const int bn = blockIdx.x * GN;
    const int tr = t >> 4;
    const int tc = t & 15;

    const int arow0 = t >> 2;
    const int ac4   = t & 3;
    const int brow0 = t >> 5;
    const int bc4   = t & 31;

    float acc[8][8] = {};

    for (int k0 = 0; k0 < K; k0 += GK) {
#pragma unroll
        for (int ii = 0; ii < 2; ++ii) {
            const int row = arow0 + ii * 64;
            const float4 a4 = *reinterpret_cast<const float4*>(
                A + (size_t)(bm + row) * K + k0 + ac4 * 4);
            As[ac4 * 4 + 0][row] = a4.x;
            As[ac4 * 4 + 1][row] = a4.y;
            As[ac4 * 4 + 2][row] = a4.z;
            As[ac4 * 4 + 3][row] = a4.w;
        }
#pragma unroll
        for (int ii = 0; ii < 2; ++ii) {
            const int row = brow0 + ii * 8;
            *reinterpret_cast<float4*>(&Bs[row][bc4 * 4]) =
                *reinterpret_cast<const float4*>(B + (size_t)(k0 + row) * N + bn + bc4 * 4);
        }
        __syncthreads();

#pragma unroll
        for (int kk = 0; kk < GK; ++kk) {
            float a[8], b[8];
            *reinterpret_cast<float4*>(a)     = *reinterpret_cast<const float4*>(&As[kk][tr * 8]);
            *reinterpret_cast<float4*>(a + 4) = *reinterpret_cast<const float4*>(&As[kk][tr * 8 + 4]);
            *reinterpret_cast<float4*>(b)     = *reinterpret_cast<const float4*>(&Bs[kk][tc * 8]);
            *reinterpret_cast<float4*>(b + 4) = *reinterpret_cast<const float4*>(&Bs[kk][tc * 8 + 4]);
#pragma unroll
            for (int i = 0; i < 8; ++i)
#pragma unroll
                for (int jj = 0; jj < 8; ++jj)
                    acc[i][jj] = fmaf(a[i], b[jj], acc[i][jj]);
        }
        __syncthreads();
    }

#pragma unroll
    for (int i = 0; i < 8; ++i) {
        float* crow = C + (size_t)(bm + tr * 8 + i) * N + bn + tc * 8;
        *reinterpret_cast<float4*>(crow)     = make_float4(acc[i][0], acc[i][1], acc[i][2], acc[i][3]);
        *reinterpret_cast<float4*>(crow + 4) = make_float4(acc[i][4], acc[i][5], acc[i][6], acc[i][7]);
    }
}

// ---------------------------------------------------------------------------
// Flash attention, anti-causal mask (keep k > q). QT=64 -> 1024 blocks,
// heavy-first remap, LDS = 40960 B (4 blocks/CU), swizzled P, rotated reads.
// launch_bounds(256,2): R3's (256,4) halved VGPRs to 64 -> scratch spill
// catastrophe (28.5 GB writes/dispatch). 128 VGPR = no spill (R2 evidence);
// 4 blocks/CU still reachable (LDS-limited), don't over-constrain registers.
// Thread (rs=t>>3, j=t&7) owns rows {rs, rs+32} x d-cols [j*16, j*16+16).
// ---------------------------------------------------------------------------
constexpr int QT = 64;
constexpr int KT = 32;

__global__ __launch_bounds__(256, 2) void attn_f32(const float* __restrict__ Q,
                                                   const float* __restrict__ Kp,
                                                   const float* __restrict__ Vp,
                                                   float* __restrict__ Op) {
    __shared__ float Ks[KT][HD];       // 16 KB
    __shared__ float Vs[KT][HD];       // 16 KB
    __shared__ float P[QT][KT];        // 8 KB, swizzled [row][kk ^ (row&7)]

    const int t = threadIdx.x;
    const int j = t & 7;
    const int rs = t >> 3;             // 0..31
    // heavy-first remap: qRank 0 -> qi 31 (full work), then 0,1,...,30 (descending)
    const int qRank = blockIdx.x >> 5; // 0..31
    const int bh = blockIdx.x & 31;
    const int h = bh & 15;
    const int b = bh >> 4;
    const int qi = (qRank == 0) ? 31 : qRank - 1;
    const int q0 = qi * QT;
    const float scale = 0.08838834764831845f;  // 1/sqrt(128)

    const size_t base = ((size_t)b * SEQ) * DIM + (size_t)h * HD;
    const float* Qb = Q + base;
    const float* Kb = Kp + base;
    const float* Vb = Vp + base;
    float* Ob = Op + base;

    // Q fragments: 2 rows x own 16 cols
    float qf[2][16];
#pragma unroll
    for (int ri = 0; ri < 2; ++ri) {
        const float* src = Qb + (size_t)(q0 + rs + 32 * ri) * DIM + j * 16;
#pragma unroll
        for (int i = 0; i < 16; i += 4)
            *reinterpret_cast<float4*>(&qf[ri][i]) = *reinterpret_cast<const float4*>(src + i);
    }

    float m[2], l[2], o[2][16];
#pragma unroll
    for (int ri = 0; ri < 2; ++ri) {
        m[ri] = -INFINITY;
        l[ri] = 0.f;
#pragma unroll
        for (int i = 0; i < 16; ++i) o[ri][i] = 0.f;
    }

    // Skip K-tiles that are fully masked for every row of this q-tile.
    // Last q-tile (qi==31) processes everything so the fully-masked row S-1
    // degenerates to uniform 1/S exactly like the reference.
    const int ktStart = (qi == SEQ / QT - 1) ? 0 : (q0 + 1) / KT;

    for (int kt = ktStart; kt < SEQ / KT; ++kt) {
        const int k0 = kt * KT;
        // stage K/V tile: contiguous-per-wave float4 writes (conflict-free)
#pragma unroll
        for (int ii = 0; ii < 4; ++ii) {
            const int id = ii * 256 + t;
            const int kr = id >> 5;
            const int c4 = id & 31;
            *reinterpret_cast<float4*>(&Ks[kr][c4 * 4]) =
                *reinterpret_cast<const float4*>(Kb + (size_t)(k0 + kr) * DIM + c4 * 4);
            *reinterpret_cast<float4*>(&Vs[kr][c4 * 4]) =
                *reinterpret_cast<const float4*>(Vb + (size_t)(k0 + kr) * DIM + c4 * 4);
        }
        __syncthreads();

        // ---- phase A: logits + per-row tile max ----
        float mt[2] = {-INFINITY, -INFINITY};
#pragma unroll 4
        for (int kk = 0; kk < KT; ++kk) {
            float kf[16];
#pragma unroll
            for (int c = 0; c < 4; ++c) {   // rotated reads: 4-way -> 2-way (free)
                const int cc = (c + j) & 3;
                *reinterpret_cast<float4*>(&kf[cc * 4]) =
                    *reinterpret_cast<const float4*>(&Ks[kk][j * 16 + cc * 4]);
            }
            const int kg = k0 + kk;
#pragma unroll
            for (int ri = 0; ri < 2; ++ri) {
                float s = 0.f;
#pragma unroll
                for (int i = 0; i < 16; ++i) s = fmaf(qf[ri][i], kf[i], s);
                s += __shfl_xor(s, 1);
                s += __shfl_xor(s, 2);
                s += __shfl_xor(s, 4);
                const int row = rs + 32 * ri;
                const int qg = q0 + row;
                const float logit = (kg > qg) ? s * scale : -FLT_MAX;
                mt[ri] = fmaxf(mt[ri], logit);
                if (j == 0) P[row][kk ^ (rs & 7)] = logit;  // swizzled store
            }
        }
        __syncthreads();

        // ---- online-softmax rescale ----
#pragma unroll
        for (int ri = 0; ri < 2; ++ri) {
            const float mn = fmaxf(m[ri], mt[ri]);
            const float corr = __expf(m[ri] - mn);
            m[ri] = mn;
            l[ri] *= corr;
#pragma unroll
            for (int i = 0; i < 16; ++i) o[ri][i] *= corr;
        }

        // ---- phase B: P*V accumulate ----
#pragma unroll 4
        for (int kk = 0; kk < KT; ++kk) {
            float vf[16];
#pragma unroll
            for (int c = 0; c < 4; ++c) {
                const int cc = (c + j) & 3;
                *reinterpret_cast<float4*>(&vf[cc * 4]) =
                    *reinterpret_cast<const float4*>(&Vs[kk][j * 16 + cc * 4]);
            }
#pragma unroll
            for (int ri = 0; ri < 2; ++ri) {
                const float p = __expf(P[rs + 32 * ri][kk ^ (rs & 7)] - m[ri]);
                l[ri] += p;
#pragma unroll
                for (int i = 0; i < 16; ++i) o[ri][i] = fmaf(p, vf[i], o[ri][i]);
            }
        }
        __syncthreads();
    }

#pragma unroll
    for (int ri = 0; ri < 2; ++ri) {
        const float inv = 1.0f / l[ri];
        float* dst = Ob + (size_t)(q0 + rs + 32 * ri) * DIM + j * 16;
#pragma unroll
        for (int i = 0; i < 16; i += 4) {
            float4 v4;
            v4.x = o[ri][i + 0] * inv;
            v4.y = o[ri][i + 1] * inv;
            v4.z = o[ri][i + 2] * inv;
            v4.w = o[ri][i + 3] * inv;
            *reinterpret_cast<float4*>(dst + i) = v4;
        }
    }
}

// ---------------------------------------------------------------------------
// Workspace layout (floats): Q | K | V | attn_out, each 4096*2048 (32 MiB).
// ---------------------------------------------------------------------------
extern "C" void kernel_launch(void* const* d_in, const int* in_sizes, int n_in,
                              void* d_out, int out_size, void* d_ws, size_t ws_size,
                              hipStream_t stream) {
    const float* x  = (const float*)d_in[0];
    const float* Wq = (const float*)d_in[1];
    const float* Wk = (const float*)d_in[2];
    const float* Wv = (const float*)d_in[3];
    const float* Wo = (const float*)d_in[4];
    float* out = (float*)d_out;

    const size_t mat = (size_t)MROWS * DIM;
    float* Qw = (float*)d_ws;
    float* Kw = Qw + mat;
    float* Vw = Kw + mat;
    float* Aw = Vw + mat;

    const dim3 blk(256);
    const dim3 ggrid(DIM / 128, MROWS / 128);
    gemm_f32<<<ggrid, blk, 0, stream>>>(x, Wq, Qw, MROWS, DIM, DIM);
    gemm_f32<<<ggrid, blk, 0, stream>>>(x, Wk, Kw, MROWS, DIM, DIM);
    gemm_f32<<<ggrid, blk, 0, stream>>>(x, Wv, Vw, MROWS, DIM, DIM);

    const dim3 agrid((SEQ / QT) * HEADS * BATCH);  // 1024 blocks, heavy-first remap inside
    attn_f32<<<agrid, blk, 0, stream>>>(Qw, Kw, Vw, Aw);

    gemm_f32<<<ggrid, blk, 0, stream>>>(Aw, Wo, out, MROWS, DIM, DIM);
}

// Round 6
// 2695.475 us; speedup vs baseline: 6.4791x; 6.4791x over previous
//
#include <hip/hip_runtime.h>
#include <float.h>
#include <math.h>

#define DIM 2048
#define HEADS 16
#define BATCH 2
#define SEQ 2048
#define HD 128              // head dim
#define MROWS (BATCH * SEQ) // 4096

// ---------------------------------------------------------------------------
// fp32 tiled GEMM: C(MxN) = A(MxK) @ B(KxN), all row-major, dims % 128 == 0.
// 128x128 tile, BK=16, 256 threads, 8x8 micro-tile per thread. (unchanged,
// known-good: ~390us each, ~56% of fp32 vector ceiling)
// ---------------------------------------------------------------------------
__global__ __launch_bounds__(256) void gemm_f32(const float* __restrict__ A,
                                                const float* __restrict__ B,
                                                float* __restrict__ C,
                                                int M, int N, int K) {
    constexpr int GM = 128, GN = 128, GK = 16;
    __shared__ float As[GK][GM + 4];
    __shared__ float Bs[GK][GN];

    const int t = threadIdx.x;
    const int bm = blockIdx.y * GM;
    const int bn = blockIdx.x * GN;
    const int tr = t >> 4;
    const int tc = t & 15;

    const int arow0 = t >> 2;
    const int ac4   = t & 3;
    const int brow0 = t >> 5;
    const int bc4   = t & 31;

    float acc[8][8] = {};

    for (int k0 = 0; k0 < K; k0 += GK) {
#pragma unroll
        for (int ii = 0; ii < 2; ++ii) {
            const int row = arow0 + ii * 64;
            const float4 a4 = *reinterpret_cast<const float4*>(
                A + (size_t)(bm + row) * K + k0 + ac4 * 4);
            As[ac4 * 4 + 0][row] = a4.x;
            As[ac4 * 4 + 1][row] = a4.y;
            As[ac4 * 4 + 2][row] = a4.z;
            As[ac4 * 4 + 3][row] = a4.w;
        }
#pragma unroll
        for (int ii = 0; ii < 2; ++ii) {
            const int row = brow0 + ii * 8;
            *reinterpret_cast<float4*>(&Bs[row][bc4 * 4]) =
                *reinterpret_cast<const float4*>(B + (size_t)(k0 + row) * N + bn + bc4 * 4);
        }
        __syncthreads();

#pragma unroll
        for (int kk = 0; kk < GK; ++kk) {
            float a[8], b[8];
            *reinterpret_cast<float4*>(a)     = *reinterpret_cast<const float4*>(&As[kk][tr * 8]);
            *reinterpret_cast<float4*>(a + 4) = *reinterpret_cast<const float4*>(&As[kk][tr * 8 + 4]);
            *reinterpret_cast<float4*>(b)     = *reinterpret_cast<const float4*>(&Bs[kk][tc * 8]);
            *reinterpret_cast<float4*>(b + 4) = *reinterpret_cast<const float4*>(&Bs[kk][tc * 8 + 4]);
#pragma unroll
            for (int i = 0; i < 8; ++i)
#pragma unroll
                for (int jj = 0; jj < 8; ++jj)
                    acc[i][jj] = fmaf(a[i], b[jj], acc[i][jj]);
        }
        __syncthreads();
    }

#pragma unroll
    for (int i = 0; i < 8; ++i) {
        float* crow = C + (size_t)(bm + tr * 8 + i) * N + bn + tc * 8;
        *reinterpret_cast<float4*>(crow)     = make_float4(acc[i][0], acc[i][1], acc[i][2], acc[i][3]);
        *reinterpret_cast<float4*>(crow + 4) = make_float4(acc[i][4], acc[i][5], acc[i][6], acc[i][7]);
    }
}

// ---------------------------------------------------------------------------
// Flash attention, anti-causal mask (keep k > q). QT=64 -> 1024 blocks,
// heavy-first remap, LDS = 40960 B, swizzled P.
//
// RULE-20 FIX vs R3/R4: no runtime-indexed register arrays. kf/vf are indexed
// with compile-time i only. Bank conflicts are instead fixed by an LDS
// column-chunk XOR swizzle: logical col c lives at phys dword c ^ ((c&0x60)>>3)
// (involution; only bits 2-3 change; float4 chunks stay contiguous).
// Read banks per j = {0,16,4,20,8,24,12,28} -> conflict-free.
// Thread (rs=t>>3, j=t&7) owns rows {rs, rs+32} x d-cols [j*16, j*16+16).
// ---------------------------------------------------------------------------
constexpr int QT = 64;
constexpr int KT = 32;

__global__ __launch_bounds__(256, 2) void attn_f32(const float* __restrict__ Q,
                                                   const float* __restrict__ Kp,
                                                   const float* __restrict__ Vp,
                                                   float* __restrict__ Op) {
    __shared__ float Ks[KT][HD];       // 16 KB, column-swizzled
    __shared__ float Vs[KT][HD];       // 16 KB, column-swizzled
    __shared__ float P[QT][KT];        // 8 KB, swizzled [row][kk ^ (row&7)]

    const int t = threadIdx.x;
    const int j = t & 7;
    const int rs = t >> 3;             // 0..31
    // heavy-first remap: qRank 0 -> qi 31 (64 tiles), then qi 0 (64), 1 (62), ...
    const int qRank = blockIdx.x >> 5; // 0..31
    const int bh = blockIdx.x & 31;
    const int h = bh & 15;
    const int b = bh >> 4;
    const int qi = (qRank == 0) ? 31 : qRank - 1;
    const int q0 = qi * QT;
    const int sw = (j & 6) << 1;       // this thread's column-chunk swizzle (bits 2-3)
    const float scale = 0.08838834764831845f;  // 1/sqrt(128)

    const size_t base = ((size_t)b * SEQ) * DIM + (size_t)h * HD;
    const float* Qb = Q + base;
    const float* Kb = Kp + base;
    const float* Vb = Vp + base;
    float* Ob = Op + base;

    // Q fragments: 2 rows x own 16 cols (global loads, compile-time reg indices)
    float qf[2][16];
#pragma unroll
    for (int ri = 0; ri < 2; ++ri) {
        const float* src = Qb + (size_t)(q0 + rs + 32 * ri) * DIM + j * 16;
#pragma unroll
        for (int i = 0; i < 16; i += 4)
            *reinterpret_cast<float4*>(&qf[ri][i]) = *reinterpret_cast<const float4*>(src + i);
    }

    float m[2], l[2], o[2][16];
#pragma unroll
    for (int ri = 0; ri < 2; ++ri) {
        m[ri] = -INFINITY;
        l[ri] = 0.f;
#pragma unroll
        for (int i = 0; i < 16; ++i) o[ri][i] = 0.f;
    }

    // Skip fully-masked K-tiles. Last q-tile (qi==31) processes everything so
    // the fully-masked row S-1 degenerates to uniform 1/S like the reference.
    const int ktStart = (qi == SEQ / QT - 1) ? 0 : (q0 + 1) / KT;

    for (int kt = ktStart; kt < SEQ / KT; ++kt) {
        const int k0 = kt * KT;
        // stage K/V tile with column swizzle: logical cols 4*c4.. -> phys chunk
#pragma unroll
        for (int ii = 0; ii < 4; ++ii) {
            const int id = ii * 256 + t;
            const int kr = id >> 5;
            const int c4 = id & 31;
            const int pc = (c4 * 4) ^ ((c4 & 24) >> 1);   // phys dword offset in row
            *reinterpret_cast<float4*>(&Ks[kr][pc]) =
                *reinterpret_cast<const float4*>(Kb + (size_t)(k0 + kr) * DIM + c4 * 4);
            *reinterpret_cast<float4*>(&Vs[kr][pc]) =
                *reinterpret_cast<const float4*>(Vb + (size_t)(k0 + kr) * DIM + c4 * 4);
        }
        __syncthreads();

        // ---- phase A: logits + per-row tile max ----
        float mt[2] = {-INFINITY, -INFINITY};
#pragma unroll 4
        for (int kk = 0; kk < KT; ++kk) {
            float kf[16];
#pragma unroll
            for (int i = 0; i < 4; ++i)    // compile-time kf index; swizzled LDS addr
                *reinterpret_cast<float4*>(&kf[i * 4]) =
                    *reinterpret_cast<const float4*>(&Ks[kk][j * 16 + ((i * 4) ^ sw)]);
            const int kg = k0 + kk;
#pragma unroll
            for (int ri = 0; ri < 2; ++ri) {
                float s = 0.f;
#pragma unroll
                for (int i = 0; i < 16; ++i) s = fmaf(qf[ri][i], kf[i], s);
                s += __shfl_xor(s, 1);
                s += __shfl_xor(s, 2);
                s += __shfl_xor(s, 4);
                const int row = rs + 32 * ri;
                const int qg = q0 + row;
                const float logit = (kg > qg) ? s * scale : -FLT_MAX;
                mt[ri] = fmaxf(mt[ri], logit);
                if (j == 0) P[row][kk ^ (rs & 7)] = logit;  // swizzled store
            }
        }
        __syncthreads();

        // ---- online-softmax rescale ----
#pragma unroll
        for (int ri = 0; ri < 2; ++ri) {
            const float mn = fmaxf(m[ri], mt[ri]);
            const float corr = __expf(m[ri] - mn);
            m[ri] = mn;
            l[ri] *= corr;
#pragma unroll
            for (int i = 0; i < 16; ++i) o[ri][i] *= corr;
        }

        // ---- phase B: P*V accumulate ----
#pragma unroll 4
        for (int kk = 0; kk < KT; ++kk) {
            float vf[16];
#pragma unroll
            for (int i = 0; i < 4; ++i)
                *reinterpret_cast<float4*>(&vf[i * 4]) =
                    *reinterpret_cast<const float4*>(&Vs[kk][j * 16 + ((i * 4) ^ sw)]);
#pragma unroll
            for (int ri = 0; ri < 2; ++ri) {
                const float p = __expf(P[rs + 32 * ri][kk ^ (rs & 7)] - m[ri]);
                l[ri] += p;
#pragma unroll
                for (int i = 0; i < 16; ++i) o[ri][i] = fmaf(p, vf[i], o[ri][i]);
            }
        }
        __syncthreads();
    }

#pragma unroll
    for (int ri = 0; ri < 2; ++ri) {
        const float inv = 1.0f / l[ri];
        float* dst = Ob + (size_t)(q0 + rs + 32 * ri) * DIM + j * 16;
#pragma unroll
        for (int i = 0; i < 16; i += 4) {
            float4 v4;
            v4.x = o[ri][i + 0] * inv;
            v4.y = o[ri][i + 1] * inv;
            v4.z = o[ri][i + 2] * inv;
            v4.w = o[ri][i + 3] * inv;
            *reinterpret_cast<float4*>(dst + i) = v4;
        }
    }
}

// ---------------------------------------------------------------------------
// Workspace layout (floats): Q | K | V | attn_out, each 4096*2048 (32 MiB).
// ---------------------------------------------------------------------------
extern "C" void kernel_launch(void* const* d_in, const int* in_sizes, int n_in,
                              void* d_out, int out_size, void* d_ws, size_t ws_size,
                              hipStream_t stream) {
    const float* x  = (const float*)d_in[0];
    const float* Wq = (const float*)d_in[1];
    const float* Wk = (const float*)d_in[2];
    const float* Wv = (const float*)d_in[3];
    const float* Wo = (const float*)d_in[4];
    float* out = (float*)d_out;

    const size_t mat = (size_t)MROWS * DIM;
    float* Qw = (float*)d_ws;
    float* Kw = Qw + mat;
    float* Vw = Kw + mat;
    float* Aw = Vw + mat;

    const dim3 blk(256);
    const dim3 ggrid(DIM / 128, MROWS / 128);
    gemm_f32<<<ggrid, blk, 0, stream>>>(x, Wq, Qw, MROWS, DIM, DIM);
    gemm_f32<<<ggrid, blk, 0, stream>>>(x, Wk, Kw, MROWS, DIM, DIM);
    gemm_f32<<<ggrid, blk, 0, stream>>>(x, Wv, Vw, MROWS, DIM, DIM);

    const dim3 agrid((SEQ / QT) * HEADS * BATCH);  // 1024 blocks, heavy-first remap inside
    attn_f32<<<agrid, blk, 0, stream>>>(Qw, Kw, Vw, Aw);

    gemm_f32<<<ggrid, blk, 0, stream>>>(Aw, Wo, out, MROWS, DIM, DIM);
}

// Round 7
// 1608.229 us; speedup vs baseline: 10.8593x; 1.6761x over previous
//
#include <hip/hip_runtime.h>
#include <float.h>
#include <math.h>

#define DIM 2048
#define HEADS 16
#define BATCH 2
#define SEQ 2048
#define HD 128              // head dim
#define MROWS (BATCH * SEQ) // 4096

typedef __attribute__((ext_vector_type(8))) short s16x8;   // 8 bf16 bits (4 VGPR)
typedef __attribute__((ext_vector_type(4))) float f32x4;   // MFMA acc

// ---- bf16 split helpers (bit-level, RNE) ----
__device__ __forceinline__ unsigned short f2bf_rne(float x) {
    unsigned int u = __float_as_uint(x);
    unsigned int r = (u + 0x7FFFu + ((u >> 16) & 1u)) >> 16;
    return (unsigned short)r;
}
__device__ __forceinline__ float bf2f(unsigned short h) {
    return __uint_as_float(((unsigned int)h) << 16);
}

// ---------------------------------------------------------------------------
// fp32 tiled GEMM (fallback path, known-good ~390us)
// ---------------------------------------------------------------------------
__global__ __launch_bounds__(256) void gemm_f32(const float* __restrict__ A,
                                                const float* __restrict__ B,
                                                float* __restrict__ C,
                                                int M, int N, int K) {
    constexpr int GM = 128, GN = 128, GK = 16;
    __shared__ float As[GK][GM + 4];
    __shared__ float Bs[GK][GN];

    const int t = threadIdx.x;
    const int bm = blockIdx.y * GM;
    const int bn = blockIdx.x * GN;
    const int tr = t >> 4;
    const int tc = t & 15;

    const int arow0 = t >> 2;
    const int ac4   = t & 3;
    const int brow0 = t >> 5;
    const int bc4   = t & 31;

    float acc[8][8] = {};

    for (int k0 = 0; k0 < K; k0 += GK) {
#pragma unroll
        for (int ii = 0; ii < 2; ++ii) {
            const int row = arow0 + ii * 64;
            const float4 a4 = *reinterpret_cast<const float4*>(
                A + (size_t)(bm + row) * K + k0 + ac4 * 4);
            As[ac4 * 4 + 0][row] = a4.x;
            As[ac4 * 4 + 1][row] = a4.y;
            As[ac4 * 4 + 2][row] = a4.z;
            As[ac4 * 4 + 3][row] = a4.w;
        }
#pragma unroll
        for (int ii = 0; ii < 2; ++ii) {
            const int row = brow0 + ii * 8;
            *reinterpret_cast<float4*>(&Bs[row][bc4 * 4]) =
                *reinterpret_cast<const float4*>(B + (size_t)(k0 + row) * N + bn + bc4 * 4);
        }
        __syncthreads();

#pragma unroll
        for (int kk = 0; kk < GK; ++kk) {
            float a[8], b[8];
            *reinterpret_cast<float4*>(a)     = *reinterpret_cast<const float4*>(&As[kk][tr * 8]);
            *reinterpret_cast<float4*>(a + 4) = *reinterpret_cast<const float4*>(&As[kk][tr * 8 + 4]);
            *reinterpret_cast<float4*>(b)     = *reinterpret_cast<const float4*>(&Bs[kk][tc * 8]);
            *reinterpret_cast<float4*>(b + 4) = *reinterpret_cast<const float4*>(&Bs[kk][tc * 8 + 4]);
#pragma unroll
            for (int i = 0; i < 8; ++i)
#pragma unroll
                for (int jj = 0; jj < 8; ++jj)
                    acc[i][jj] = fmaf(a[i], b[jj], acc[i][jj]);
        }
        __syncthreads();
    }

#pragma unroll
    for (int i = 0; i < 8; ++i) {
        float* crow = C + (size_t)(bm + tr * 8 + i) * N + bn + tc * 8;
        *reinterpret_cast<float4*>(crow)     = make_float4(acc[i][0], acc[i][1], acc[i][2], acc[i][3]);
        *reinterpret_cast<float4*>(crow + 4) = make_float4(acc[i][4], acc[i][5], acc[i][6], acc[i][7]);
    }
}

// ---------------------------------------------------------------------------
// conv_split: fp32 [n] -> bf16 hi[n], lo[n] (flat). 4096 blocks x 256 thr x 8.
// ---------------------------------------------------------------------------
__global__ __launch_bounds__(256) void conv_split(const float* __restrict__ X,
                                                  unsigned short* __restrict__ H,
                                                  unsigned short* __restrict__ L) {
    const size_t i0 = ((size_t)blockIdx.x * 256 + threadIdx.x) * 8;
#pragma unroll
    for (int v = 0; v < 2; ++v) {
        const float4 x4 = *reinterpret_cast<const float4*>(X + i0 + v * 4);
        ushort4 h4, l4;
        h4.x = f2bf_rne(x4.x); l4.x = f2bf_rne(x4.x - bf2f(h4.x));
        h4.y = f2bf_rne(x4.y); l4.y = f2bf_rne(x4.y - bf2f(h4.y));
        h4.z = f2bf_rne(x4.z); l4.z = f2bf_rne(x4.z - bf2f(h4.z));
        h4.w = f2bf_rne(x4.w); l4.w = f2bf_rne(x4.w - bf2f(h4.w));
        *reinterpret_cast<ushort4*>(H + i0 + v * 4) = h4;
        *reinterpret_cast<ushort4*>(L + i0 + v * 4) = l4;
    }
}

// ---------------------------------------------------------------------------
// convT_split: W fp32 [K][N] -> WT hi/lo bf16 [N][K]. 32x32 tiles, grid(64,64).
// ---------------------------------------------------------------------------
__global__ __launch_bounds__(256) void convT_split(const float* __restrict__ W,
                                                   unsigned short* __restrict__ TH,
                                                   unsigned short* __restrict__ TL) {
    __shared__ float tile[32][33];
    const int k0 = blockIdx.x * 32;
    const int n0 = blockIdx.y * 32;
    const int tx = threadIdx.x & 31;
    const int ty = threadIdx.x >> 5;   // 0..7
#pragma unroll
    for (int i = 0; i < 4; ++i)
        tile[ty + 8 * i][tx] = W[(size_t)(k0 + ty + 8 * i) * DIM + n0 + tx];
    __syncthreads();
#pragma unroll
    for (int i = 0; i < 4; ++i) {
        const float v = tile[tx][ty + 8 * i];
        const unsigned short h = f2bf_rne(v);
        const unsigned short l = f2bf_rne(v - bf2f(h));
        const size_t dst = (size_t)(n0 + ty + 8 * i) * DIM + k0 + tx;
        TH[dst] = h;
        TL[dst] = l;
    }
}

// ---------------------------------------------------------------------------
// gemm_bf16x3: C[M][N] fp32 = (Ah+Al)[M][K] @ (Bh+Bl)^T, B given as BT[N][K].
// 3-term: Ah*Bh + Ah*Bl + Al*Bh via mfma_f32_16x16x32_bf16.
// 128x128 tile, BK=32, 256 thr = 4 waves in 2x2, 4x4 frags each (64x64/wave).
// LDS 16B-chunk XOR swizzle: phys_chunk = log_chunk ^ ((row>>1)&3) ->
// structurally-optimal (8-slot) b128 reads/writes. Fragment k-mapping is a
// fixed permutation shared by A and B => MFMA sum is permutation-invariant.
// C/D layout (m89-verified): col = lane&15, row = (lane>>4)*4 + reg.
// ---------------------------------------------------------------------------
__global__ __launch_bounds__(256) void gemm_bf16x3(
    const unsigned short* __restrict__ Ah_g, const unsigned short* __restrict__ Al_g,
    const unsigned short* __restrict__ Bh_g, const unsigned short* __restrict__ Bl_g,
    float* __restrict__ C, int M, int N, int K) {
    __shared__ short Ah[128][32], Al[128][32], Bh[128][32], Bl[128][32]; // 32 KB

    const int t = threadIdx.x;
    const int m0 = blockIdx.y * 128;
    const int n0 = blockIdx.x * 128;
    const int w  = t >> 6, lane = t & 63;
    const int wr = w >> 1, wc = w & 1;
    const int lr = lane & 15, g = lane >> 4;
    const int pcl = g ^ ((lr >> 1) & 3);      // read-side phys chunk (same for all frags)

    const int srow = t >> 1;                  // staging row 0..127
    const int sc   = (t & 1) * 2;             // first 16B-chunk this thread stages
    const int ssw  = (srow >> 1) & 3;         // write-side swizzle
    const int p0 = sc ^ ssw, p1 = (sc + 1) ^ ssw;

    f32x4 acc[4][4];
#pragma unroll
    for (int i = 0; i < 4; ++i)
#pragma unroll
        for (int j = 0; j < 4; ++j) acc[i][j] = (f32x4){0.f, 0.f, 0.f, 0.f};

    for (int k0 = 0; k0 < K; k0 += 32) {
        // ---- stage: each thread 32B (2 chunks) per array ----
        const size_t aoff = (size_t)(m0 + srow) * K + k0 + sc * 8;
        const size_t boff = (size_t)(n0 + srow) * K + k0 + sc * 8;
        const s16x8 va0 = *reinterpret_cast<const s16x8*>(Ah_g + aoff);
        const s16x8 va1 = *reinterpret_cast<const s16x8*>(Ah_g + aoff + 8);
        const s16x8 vb0 = *reinterpret_cast<const s16x8*>(Al_g + aoff);
        const s16x8 vb1 = *reinterpret_cast<const s16x8*>(Al_g + aoff + 8);
        const s16x8 vc0 = *reinterpret_cast<const s16x8*>(Bh_g + boff);
        const s16x8 vc1 = *reinterpret_cast<const s16x8*>(Bh_g + boff + 8);
        const s16x8 vd0 = *reinterpret_cast<const s16x8*>(Bl_g + boff);
        const s16x8 vd1 = *reinterpret_cast<const s16x8*>(Bl_g + boff + 8);
        *reinterpret_cast<s16x8*>(&Ah[srow][p0 * 8]) = va0;
        *reinterpret_cast<s16x8*>(&Ah[srow][p1 * 8]) = va1;
        *reinterpret_cast<s16x8*>(&Al[srow][p0 * 8]) = vb0;
        *reinterpret_cast<s16x8*>(&Al[srow][p1 * 8]) = vb1;
        *reinterpret_cast<s16x8*>(&Bh[srow][p0 * 8]) = vc0;
        *reinterpret_cast<s16x8*>(&Bh[srow][p1 * 8]) = vc1;
        *reinterpret_cast<s16x8*>(&Bl[srow][p0 * 8]) = vd0;
        *reinterpret_cast<s16x8*>(&Bl[srow][p1 * 8]) = vd1;
        __syncthreads();

        // ---- fragments ----
        s16x8 afh[4], afl[4], bfh[4], bfl[4];
#pragma unroll
        for (int i = 0; i < 4; ++i) {
            const int r = wr * 64 + i * 16 + lr;
            afh[i] = *reinterpret_cast<const s16x8*>(&Ah[r][pcl * 8]);
            afl[i] = *reinterpret_cast<const s16x8*>(&Al[r][pcl * 8]);
        }
#pragma unroll
        for (int j = 0; j < 4; ++j) {
            const int r = wc * 64 + j * 16 + lr;
            bfh[j] = *reinterpret_cast<const s16x8*>(&Bh[r][pcl * 8]);
            bfl[j] = *reinterpret_cast<const s16x8*>(&Bl[r][pcl * 8]);
        }

        // ---- 48 MFMA ----
#pragma unroll
        for (int i = 0; i < 4; ++i)
#pragma unroll
            for (int j = 0; j < 4; ++j) {
                acc[i][j] = __builtin_amdgcn_mfma_f32_16x16x32_bf16(afh[i], bfh[j], acc[i][j], 0, 0, 0);
                acc[i][j] = __builtin_amdgcn_mfma_f32_16x16x32_bf16(afh[i], bfl[j], acc[i][j], 0, 0, 0);
                acc[i][j] = __builtin_amdgcn_mfma_f32_16x16x32_bf16(afl[i], bfh[j], acc[i][j], 0, 0, 0);
            }
        __syncthreads();
    }

    // ---- epilogue: col = lane&15, row = g*4 + reg ----
#pragma unroll
    for (int i = 0; i < 4; ++i) {
#pragma unroll
        for (int j = 0; j < 4; ++j) {
            const size_t base = (size_t)(m0 + wr * 64 + i * 16 + g * 4) * N
                              + n0 + wc * 64 + j * 16 + lr;
#pragma unroll
            for (int r = 0; r < 4; ++r)
                C[base + (size_t)r * N] = acc[i][j][r];
        }
    }
}

// ---------------------------------------------------------------------------
// Flash attention, anti-causal mask (unchanged from R6: 1160us, 0 conflicts).
// ---------------------------------------------------------------------------
constexpr int QT = 64;
constexpr int KT = 32;

__global__ __launch_bounds__(256, 2) void attn_f32(const float* __restrict__ Q,
                                                   const float* __restrict__ Kp,
                                                   const float* __restrict__ Vp,
                                                   float* __restrict__ Op) {
    __shared__ float Ks[KT][HD];
    __shared__ float Vs[KT][HD];
    __shared__ float P[QT][KT];

    const int t = threadIdx.x;
    const int j = t & 7;
    const int rs = t >> 3;
    const int qRank = blockIdx.x >> 5;
    const int bh = blockIdx.x & 31;
    const int h = bh & 15;
    const int b = bh >> 4;
    const int qi = (qRank == 0) ? 31 : qRank - 1;
    const int q0 = qi * QT;
    const int sw = (j & 6) << 1;
    const float scale = 0.08838834764831845f;

    const size_t base = ((size_t)b * SEQ) * DIM + (size_t)h * HD;
    const float* Qb = Q + base;
    const float* Kb = Kp + base;
    const float* Vb = Vp + base;
    float* Ob = Op + base;

    float qf[2][16];
#pragma unroll
    for (int ri = 0; ri < 2; ++ri) {
        const float* src = Qb + (size_t)(q0 + rs + 32 * ri) * DIM + j * 16;
#pragma unroll
        for (int i = 0; i < 16; i += 4)
            *reinterpret_cast<float4*>(&qf[ri][i]) = *reinterpret_cast<const float4*>(src + i);
    }

    float m[2], l[2], o[2][16];
#pragma unroll
    for (int ri = 0; ri < 2; ++ri) {
        m[ri] = -INFINITY;
        l[ri] = 0.f;
#pragma unroll
        for (int i = 0; i < 16; ++i) o[ri][i] = 0.f;
    }

    const int ktStart = (qi == SEQ / QT - 1) ? 0 : (q0 + 1) / KT;

    for (int kt = ktStart; kt < SEQ / KT; ++kt) {
        const int k0 = kt * KT;
#pragma unroll
        for (int ii = 0; ii < 4; ++ii) {
            const int id = ii * 256 + t;
            const int kr = id >> 5;
            const int c4 = id & 31;
            const int pc = (c4 * 4) ^ ((c4 & 24) >> 1);
            *reinterpret_cast<float4*>(&Ks[kr][pc]) =
                *reinterpret_cast<const float4*>(Kb + (size_t)(k0 + kr) * DIM + c4 * 4);
            *reinterpret_cast<float4*>(&Vs[kr][pc]) =
                *reinterpret_cast<const float4*>(Vb + (size_t)(k0 + kr) * DIM + c4 * 4);
        }
        __syncthreads();

        float mt[2] = {-INFINITY, -INFINITY};
#pragma unroll 4
        for (int kk = 0; kk < KT; ++kk) {
            float kf[16];
#pragma unroll
            for (int i = 0; i < 4; ++i)
                *reinterpret_cast<float4*>(&kf[i * 4]) =
                    *reinterpret_cast<const float4*>(&Ks[kk][j * 16 + ((i * 4) ^ sw)]);
            const int kg = k0 + kk;
#pragma unroll
            for (int ri = 0; ri < 2; ++ri) {
                float s = 0.f;
#pragma unroll
                for (int i = 0; i < 16; ++i) s = fmaf(qf[ri][i], kf[i], s);
                s += __shfl_xor(s, 1);
                s += __shfl_xor(s, 2);
                s += __shfl_xor(s, 4);
                const int row = rs + 32 * ri;
                const int qg = q0 + row;
                const float logit = (kg > qg) ? s * scale : -FLT_MAX;
                mt[ri] = fmaxf(mt[ri], logit);
                if (j == 0) P[row][kk ^ (rs & 7)] = logit;
            }
        }
        __syncthreads();

#pragma unroll
        for (int ri = 0; ri < 2; ++ri) {
            const float mn = fmaxf(m[ri], mt[ri]);
            const float corr = __expf(m[ri] - mn);
            m[ri] = mn;
            l[ri] *= corr;
#pragma unroll
            for (int i = 0; i < 16; ++i) o[ri][i] *= corr;
        }

#pragma unroll 4
        for (int kk = 0; kk < KT; ++kk) {
            float vf[16];
#pragma unroll
            for (int i = 0; i < 4; ++i)
                *reinterpret_cast<float4*>(&vf[i * 4]) =
                    *reinterpret_cast<const float4*>(&Vs[kk][j * 16 + ((i * 4) ^ sw)]);
#pragma unroll
            for (int ri = 0; ri < 2; ++ri) {
                const float p = __expf(P[rs + 32 * ri][kk ^ (rs & 7)] - m[ri]);
                l[ri] += p;
#pragma unroll
                for (int i = 0; i < 16; ++i) o[ri][i] = fmaf(p, vf[i], o[ri][i]);
            }
        }
        __syncthreads();
    }

#pragma unroll
    for (int ri = 0; ri < 2; ++ri) {
        const float inv = 1.0f / l[ri];
        float* dst = Ob + (size_t)(q0 + rs + 32 * ri) * DIM + j * 16;
#pragma unroll
        for (int i = 0; i < 16; i += 4) {
            float4 v4;
            v4.x = o[ri][i + 0] * inv;
            v4.y = o[ri][i + 1] * inv;
            v4.z = o[ri][i + 2] * inv;
            v4.w = o[ri][i + 3] * inv;
            *reinterpret_cast<float4*>(dst + i) = v4;
        }
    }
}

// ---------------------------------------------------------------------------
// Workspace (bytes):
//   Qw/Kw/Vw/Aw fp32: 4 x 33,554,432          = 134,217,728
//   xh/xl bf16 (reused for Aw hi/lo): 2 x 16,777,216 = 33,554,432
//   wth/wtl bf16 transposed slot: 2 x 8,388,608      = 16,777,216
//   total = 184,549,376.  Fallback to fp32 path if ws smaller.
// ---------------------------------------------------------------------------
extern "C" void kernel_launch(void* const* d_in, const int* in_sizes, int n_in,
                              void* d_out, int out_size, void* d_ws, size_t ws_size,
                              hipStream_t stream) {
    const float* x  = (const float*)d_in[0];
    const float* Wq = (const float*)d_in[1];
    const float* Wk = (const float*)d_in[2];
    const float* Wv = (const float*)d_in[3];
    const float* Wo = (const float*)d_in[4];
    float* out = (float*)d_out;

    const size_t mat = (size_t)MROWS * DIM;      // 8,388,608 elements
    char* ws = (char*)d_ws;
    float* Qw = (float*)(ws);
    float* Kw = (float*)(ws + 33554432);
    float* Vw = (float*)(ws + 67108864);
    float* Aw = (float*)(ws + 100663296);

    const dim3 blk(256);
    const dim3 agrid((SEQ / QT) * HEADS * BATCH);
    const size_t NEED = 184549376ull;

    if (ws_size >= NEED) {
        unsigned short* xh  = (unsigned short*)(ws + 134217728);
        unsigned short* xl  = (unsigned short*)(ws + 150994944);
        unsigned short* wth = (unsigned short*)(ws + 167772160);
        unsigned short* wtl = (unsigned short*)(ws + 176160768);

        const dim3 cgrid(4096);               // mat/ (256*8)
        const dim3 tgrid(DIM / 32, DIM / 32); // 64x64
        const dim3 ggrid(DIM / 128, MROWS / 128);

        conv_split<<<cgrid, blk, 0, stream>>>(x, xh, xl);

        convT_split<<<tgrid, blk, 0, stream>>>(Wq, wth, wtl);
        gemm_bf16x3<<<ggrid, blk, 0, stream>>>(xh, xl, wth, wtl, Qw, MROWS, DIM, DIM);
        convT_split<<<tgrid, blk, 0, stream>>>(Wk, wth, wtl);
        gemm_bf16x3<<<ggrid, blk, 0, stream>>>(xh, xl, wth, wtl, Kw, MROWS, DIM, DIM);
        convT_split<<<tgrid, blk, 0, stream>>>(Wv, wth, wtl);
        gemm_bf16x3<<<ggrid, blk, 0, stream>>>(xh, xl, wth, wtl, Vw, MROWS, DIM, DIM);

        attn_f32<<<agrid, blk, 0, stream>>>(Qw, Kw, Vw, Aw);

        conv_split<<<cgrid, blk, 0, stream>>>(Aw, xh, xl);   // reuse for attn-out
        convT_split<<<tgrid, blk, 0, stream>>>(Wo, wth, wtl);
        gemm_bf16x3<<<ggrid, blk, 0, stream>>>(xh, xl, wth, wtl, out, MROWS, DIM, DIM);
    } else {
        const dim3 ggrid(DIM / 128, MROWS / 128);
        gemm_f32<<<ggrid, blk, 0, stream>>>(x, Wq, Qw, MROWS, DIM, DIM);
        gemm_f32<<<ggrid, blk, 0, stream>>>(x, Wk, Kw, MROWS, DIM, DIM);
        gemm_f32<<<ggrid, blk, 0, stream>>>(x, Wv, Vw, MROWS, DIM, DIM);
        attn_f32<<<agrid, blk, 0, stream>>>(Qw, Kw, Vw, Aw);
        gemm_f32<<<ggrid, blk, 0, stream>>>(Aw, Wo, out, MROWS, DIM, DIM);
    }
}

// Round 9
// 1038.285 us; speedup vs baseline: 16.8202x; 1.5489x over previous
//
#include <hip/hip_runtime.h>
#include <hip/hip_bf16.h>
#include <float.h>
#include <math.h>

#define DIM 2048
#define HEADS 16
#define BATCH 2
#define SEQ 2048
#define HD 128              // head dim
#define MROWS (BATCH * SEQ) // 4096

typedef __attribute__((ext_vector_type(8))) short s16x8;   // 8 bf16 bits (4 VGPR)
typedef __attribute__((ext_vector_type(4))) float f32x4;   // MFMA acc

// ---- bf16 split helpers ----
__device__ __forceinline__ unsigned short f2bf_rne(float x) {
    unsigned int u = __float_as_uint(x);
    unsigned int r = (u + 0x7FFFu + ((u >> 16) & 1u)) >> 16;
    return (unsigned short)r;
}
__device__ __forceinline__ float bf2f(unsigned short h) {
    return __uint_as_float(((unsigned int)h) << 16);
}
// native-cast split (compiler emits v_cvt_pk_bf16_f32 pairs)
__device__ __forceinline__ void split1(float x, short& h, short& l) {
    __hip_bfloat16 hb = __float2bfloat16(x);
    h = (short)__bfloat16_as_ushort(hb);
    l = (short)__bfloat16_as_ushort(__float2bfloat16(x - __bfloat162float(hb)));
}

// ---------------------------------------------------------------------------
// fp32 tiled GEMM (fallback path)
// ---------------------------------------------------------------------------
__global__ __launch_bounds__(256) void gemm_f32(const float* __restrict__ A,
                                                const float* __restrict__ B,
                                                float* __restrict__ C,
                                                int M, int N, int K) {
    constexpr int GM = 128, GN = 128, GK = 16;
    __shared__ float As[GK][GM + 4];
    __shared__ float Bs[GK][GN];

    const int t = threadIdx.x;
    const int bm = blockIdx.y * GM;
    const int bn = blockIdx.x * GN;
    const int tr = t >> 4;
    const int tc = t & 15;

    const int arow0 = t >> 2;
    const int ac4   = t & 3;
    const int brow0 = t >> 5;
    const int bc4   = t & 31;

    float acc[8][8] = {};

    for (int k0 = 0; k0 < K; k0 += GK) {
#pragma unroll
        for (int ii = 0; ii < 2; ++ii) {
            const int row = arow0 + ii * 64;
            const float4 a4 = *reinterpret_cast<const float4*>(
                A + (size_t)(bm + row) * K + k0 + ac4 * 4);
            As[ac4 * 4 + 0][row] = a4.x;
            As[ac4 * 4 + 1][row] = a4.y;
            As[ac4 * 4 + 2][row] = a4.z;
            As[ac4 * 4 + 3][row] = a4.w;
        }
#pragma unroll
        for (int ii = 0; ii < 2; ++ii) {
            const int row = brow0 + ii * 8;
            *reinterpret_cast<float4*>(&Bs[row][bc4 * 4]) =
                *reinterpret_cast<const float4*>(B + (size_t)(k0 + row) * N + bn + bc4 * 4);
        }
        __syncthreads();

#pragma unroll
        for (int kk = 0; kk < GK; ++kk) {
            float a[8], b[8];
            *reinterpret_cast<float4*>(a)     = *reinterpret_cast<const float4*>(&As[kk][tr * 8]);
            *reinterpret_cast<float4*>(a + 4) = *reinterpret_cast<const float4*>(&As[kk][tr * 8 + 4]);
            *reinterpret_cast<float4*>(b)     = *reinterpret_cast<const float4*>(&Bs[kk][tc * 8]);
            *reinterpret_cast<float4*>(b + 4) = *reinterpret_cast<const float4*>(&Bs[kk][tc * 8 + 4]);
#pragma unroll
            for (int i = 0; i < 8; ++i)
#pragma unroll
                for (int jj = 0; jj < 8; ++jj)
                    acc[i][jj] = fmaf(a[i], b[jj], acc[i][jj]);
        }
        __syncthreads();
    }

#pragma unroll
    for (int i = 0; i < 8; ++i) {
        float* crow = C + (size_t)(bm + tr * 8 + i) * N + bn + tc * 8;
        *reinterpret_cast<float4*>(crow)     = make_float4(acc[i][0], acc[i][1], acc[i][2], acc[i][3]);
        *reinterpret_cast<float4*>(crow + 4) = make_float4(acc[i][4], acc[i][5], acc[i][6], acc[i][7]);
    }
}

// ---------------------------------------------------------------------------
// conv_split: fp32 [n] -> bf16 hi[n], lo[n] (flat).
// ---------------------------------------------------------------------------
__global__ __launch_bounds__(256) void conv_split(const float* __restrict__ X,
                                                  unsigned short* __restrict__ H,
                                                  unsigned short* __restrict__ L) {
    const size_t i0 = ((size_t)blockIdx.x * 256 + threadIdx.x) * 8;
#pragma unroll
    for (int v = 0; v < 2; ++v) {
        const float4 x4 = *reinterpret_cast<const float4*>(X + i0 + v * 4);
        ushort4 h4, l4;
        h4.x = f2bf_rne(x4.x); l4.x = f2bf_rne(x4.x - bf2f(h4.x));
        h4.y = f2bf_rne(x4.y); l4.y = f2bf_rne(x4.y - bf2f(h4.y));
        h4.z = f2bf_rne(x4.z); l4.z = f2bf_rne(x4.z - bf2f(h4.z));
        h4.w = f2bf_rne(x4.w); l4.w = f2bf_rne(x4.w - bf2f(h4.w));
        *reinterpret_cast<ushort4*>(H + i0 + v * 4) = h4;
        *reinterpret_cast<ushort4*>(L + i0 + v * 4) = l4;
    }
}

// ---------------------------------------------------------------------------
// convT_split: W fp32 [K][N] -> WT hi/lo bf16 [N][K]. 32x32 tiles.
// ---------------------------------------------------------------------------
__global__ __launch_bounds__(256) void convT_split(const float* __restrict__ W,
                                                   unsigned short* __restrict__ TH,
                                                   unsigned short* __restrict__ TL) {
    __shared__ float tile[32][33];
    const int k0 = blockIdx.x * 32;
    const int n0 = blockIdx.y * 32;
    const int tx = threadIdx.x & 31;
    const int ty = threadIdx.x >> 5;   // 0..7
#pragma unroll
    for (int i = 0; i < 4; ++i)
        tile[ty + 8 * i][tx] = W[(size_t)(k0 + ty + 8 * i) * DIM + n0 + tx];
    __syncthreads();
#pragma unroll
    for (int i = 0; i < 4; ++i) {
        const float v = tile[tx][ty + 8 * i];
        const unsigned short h = f2bf_rne(v);
        const unsigned short l = f2bf_rne(v - bf2f(h));
        const size_t dst = (size_t)(n0 + ty + 8 * i) * DIM + k0 + tx;
        TH[dst] = h;
        TL[dst] = l;
    }
}

// ---------------------------------------------------------------------------
// gemm_bf16x3 (verified R7: C = (Ah+Al) @ (Bh+Bl)^T, 3-term MFMA)
// ---------------------------------------------------------------------------
__global__ __launch_bounds__(256) void gemm_bf16x3(
    const unsigned short* __restrict__ Ah_g, const unsigned short* __restrict__ Al_g,
    const unsigned short* __restrict__ Bh_g, const unsigned short* __restrict__ Bl_g,
    float* __restrict__ C, int M, int N, int K) {
    __shared__ short Ah[128][32], Al[128][32], Bh[128][32], Bl[128][32];

    const int t = threadIdx.x;
    const int m0 = blockIdx.y * 128;
    const int n0 = blockIdx.x * 128;
    const int w  = t >> 6, lane = t & 63;
    const int wr = w >> 1, wc = w & 1;
    const int lr = lane & 15, g = lane >> 4;
    const int pcl = g ^ ((lr >> 1) & 3);

    const int srow = t >> 1;
    const int sc   = (t & 1) * 2;
    const int ssw  = (srow >> 1) & 3;
    const int p0 = sc ^ ssw, p1 = (sc + 1) ^ ssw;

    f32x4 acc[4][4];
#pragma unroll
    for (int i = 0; i < 4; ++i)
#pragma unroll
        for (int j = 0; j < 4; ++j) acc[i][j] = (f32x4){0.f, 0.f, 0.f, 0.f};

    for (int k0 = 0; k0 < K; k0 += 32) {
        const size_t aoff = (size_t)(m0 + srow) * K + k0 + sc * 8;
        const size_t boff = (size_t)(n0 + srow) * K + k0 + sc * 8;
        const s16x8 va0 = *reinterpret_cast<const s16x8*>(Ah_g + aoff);
        const s16x8 va1 = *reinterpret_cast<const s16x8*>(Ah_g + aoff + 8);
        const s16x8 vb0 = *reinterpret_cast<const s16x8*>(Al_g + aoff);
        const s16x8 vb1 = *reinterpret_cast<const s16x8*>(Al_g + aoff + 8);
        const s16x8 vc0 = *reinterpret_cast<const s16x8*>(Bh_g + boff);
        const s16x8 vc1 = *reinterpret_cast<const s16x8*>(Bh_g + boff + 8);
        const s16x8 vd0 = *reinterpret_cast<const s16x8*>(Bl_g + boff);
        const s16x8 vd1 = *reinterpret_cast<const s16x8*>(Bl_g + boff + 8);
        *reinterpret_cast<s16x8*>(&Ah[srow][p0 * 8]) = va0;
        *reinterpret_cast<s16x8*>(&Ah[srow][p1 * 8]) = va1;
        *reinterpret_cast<s16x8*>(&Al[srow][p0 * 8]) = vb0;
        *reinterpret_cast<s16x8*>(&Al[srow][p1 * 8]) = vb1;
        *reinterpret_cast<s16x8*>(&Bh[srow][p0 * 8]) = vc0;
        *reinterpret_cast<s16x8*>(&Bh[srow][p1 * 8]) = vc1;
        *reinterpret_cast<s16x8*>(&Bl[srow][p0 * 8]) = vd0;
        *reinterpret_cast<s16x8*>(&Bl[srow][p1 * 8]) = vd1;
        __syncthreads();

        s16x8 afh[4], afl[4], bfh[4], bfl[4];
#pragma unroll
        for (int i = 0; i < 4; ++i) {
            const int r = wr * 64 + i * 16 + lr;
            afh[i] = *reinterpret_cast<const s16x8*>(&Ah[r][pcl * 8]);
            afl[i] = *reinterpret_cast<const s16x8*>(&Al[r][pcl * 8]);
        }
#pragma unroll
        for (int j = 0; j < 4; ++j) {
            const int r = wc * 64 + j * 16 + lr;
            bfh[j] = *reinterpret_cast<const s16x8*>(&Bh[r][pcl * 8]);
            bfl[j] = *reinterpret_cast<const s16x8*>(&Bl[r][pcl * 8]);
        }

#pragma unroll
        for (int i = 0; i < 4; ++i)
#pragma unroll
            for (int j = 0; j < 4; ++j) {
                acc[i][j] = __builtin_amdgcn_mfma_f32_16x16x32_bf16(afh[i], bfh[j], acc[i][j], 0, 0, 0);
                acc[i][j] = __builtin_amdgcn_mfma_f32_16x16x32_bf16(afh[i], bfl[j], acc[i][j], 0, 0, 0);
                acc[i][j] = __builtin_amdgcn_mfma_f32_16x16x32_bf16(afl[i], bfh[j], acc[i][j], 0, 0, 0);
            }
        __syncthreads();
    }

#pragma unroll
    for (int i = 0; i < 4; ++i) {
#pragma unroll
        for (int j = 0; j < 4; ++j) {
            const size_t base = (size_t)(m0 + wr * 64 + i * 16 + g * 4) * N
                              + n0 + wc * 64 + j * 16 + lr;
#pragma unroll
            for (int r = 0; r < 4; ++r)
                C[base + (size_t)r * N] = acc[i][j][r];
        }
    }
}

// ---------------------------------------------------------------------------
// attn_mfma: flash attention with bf16x3 MFMA for QK^T and PV.
// Anti-causal mask (keep k > q), same tile-skip + heavy-first as attn_f32.
// Block = 4 waves; wave w owns q-rows [q0+w*16, +16). K-tile = 32 keys.
// (design notes as R8; compile fix: vector-lane writes go through temporaries)
// LDS total 48128 B -> 3 blocks/CU.
// ---------------------------------------------------------------------------
constexpr int QT = 64;
constexpr int AKT = 32;

__global__ __launch_bounds__(256) void attn_mfma(const float* __restrict__ Q,
                                                 const float* __restrict__ Kp,
                                                 const float* __restrict__ Vp,
                                                 float* __restrict__ Op) {
    __shared__ short Kh[AKT][136], Kl[AKT][136];   // 17408 B
    __shared__ short VTh[128][40], VTl[128][40];   // 20480 B
    __shared__ short Ph[4][16][40], Pl[4][16][40]; // 10240 B

    const int t = threadIdx.x;
    const int w = t >> 6;            // wave 0..3
    const int lane = t & 63;
    const int lr = lane & 15;        // A-row / C-col index
    const int g  = lane >> 4;        // k-chunk / C-row-group

    // heavy-first remap (identical to attn_f32)
    const int qRank = blockIdx.x >> 5;
    const int bh = blockIdx.x & 31;
    const int h = bh & 15;
    const int b = bh >> 4;
    const int qi = (qRank == 0) ? 31 : qRank - 1;
    const int q0 = qi * QT;
    const float scale = 0.08838834764831845f;  // 1/sqrt(128)

    const size_t base = ((size_t)b * SEQ) * DIM + (size_t)h * HD;
    const float* Qb = Q + base;
    const float* Kb = Kp + base;
    const float* Vb = Vp + base;
    float* Ob = Op + base;

    // ---- Q fragments: lane holds row q0+w*16+lr, k-dims c*32+g*8..+8 ----
    s16x8 qh[4], ql[4];
    {
        const float* qsrc = Qb + (size_t)(q0 + w * 16 + lr) * DIM + g * 8;
#pragma unroll
        for (int c = 0; c < 4; ++c) {
            const float4 a  = *reinterpret_cast<const float4*>(qsrc + c * 32);
            const float4 b2 = *reinterpret_cast<const float4*>(qsrc + c * 32 + 4);
            short hh, ll;
            split1(a.x,  hh, ll); qh[c][0] = hh; ql[c][0] = ll;
            split1(a.y,  hh, ll); qh[c][1] = hh; ql[c][1] = ll;
            split1(a.z,  hh, ll); qh[c][2] = hh; ql[c][2] = ll;
            split1(a.w,  hh, ll); qh[c][3] = hh; ql[c][3] = ll;
            split1(b2.x, hh, ll); qh[c][4] = hh; ql[c][4] = ll;
            split1(b2.y, hh, ll); qh[c][5] = hh; ql[c][5] = ll;
            split1(b2.z, hh, ll); qh[c][6] = hh; ql[c][6] = ll;
            split1(b2.w, hh, ll); qh[c][7] = hh; ql[c][7] = ll;
        }
    }

    f32x4 oacc[8];
#pragma unroll
    for (int s2 = 0; s2 < 8; ++s2) oacc[s2] = (f32x4){0.f, 0.f, 0.f, 0.f};
    float m[4], l[4];
#pragma unroll
    for (int r = 0; r < 4; ++r) { m[r] = -INFINITY; l[r] = 0.f; }

    const int ktStart = (qi == SEQ / QT - 1) ? 0 : (q0 + 1) / AKT;

    for (int kt = ktStart; kt < SEQ / AKT; ++kt) {
        const int k0 = kt * AKT;
        __syncthreads();   // previous tile's LDS readers done

        // ---- stage K (row-major) + V (transposed), fp32 -> bf16 hi/lo ----
#pragma unroll
        for (int ii = 0; ii < 4; ++ii) {
            const int id = ii * 256 + t;
            const int kr = id >> 5;
            const int c4 = id & 31;
            {
                const float4 v = *reinterpret_cast<const float4*>(
                    Kb + (size_t)(k0 + kr) * DIM + c4 * 4);
                short4 hh, ll;
                split1(v.x, hh.x, ll.x); split1(v.y, hh.y, ll.y);
                split1(v.z, hh.z, ll.z); split1(v.w, hh.w, ll.w);
                *reinterpret_cast<short4*>(&Kh[kr][c4 * 4]) = hh;
                *reinterpret_cast<short4*>(&Kl[kr][c4 * 4]) = ll;
            }
            {
                const float4 v = *reinterpret_cast<const float4*>(
                    Vb + (size_t)(k0 + kr) * DIM + c4 * 4);
                short hh, ll;
                split1(v.x, hh, ll); VTh[c4 * 4 + 0][kr] = hh; VTl[c4 * 4 + 0][kr] = ll;
                split1(v.y, hh, ll); VTh[c4 * 4 + 1][kr] = hh; VTl[c4 * 4 + 1][kr] = ll;
                split1(v.z, hh, ll); VTh[c4 * 4 + 2][kr] = hh; VTl[c4 * 4 + 2][kr] = ll;
                split1(v.w, hh, ll); VTh[c4 * 4 + 3][kr] = hh; VTl[c4 * 4 + 3][kr] = ll;
            }
        }
        __syncthreads();

        // ---- QK^T: 2 k-subtiles x 4 d-chunks x 3 terms ----
        f32x4 sacc[2];
        sacc[0] = (f32x4){0.f, 0.f, 0.f, 0.f};
        sacc[1] = (f32x4){0.f, 0.f, 0.f, 0.f};
#pragma unroll
        for (int sub = 0; sub < 2; ++sub) {
#pragma unroll
            for (int c = 0; c < 4; ++c) {
                const s16x8 kfh = *reinterpret_cast<const s16x8*>(&Kh[sub * 16 + lr][c * 32 + g * 8]);
                const s16x8 kfl = *reinterpret_cast<const s16x8*>(&Kl[sub * 16 + lr][c * 32 + g * 8]);
                sacc[sub] = __builtin_amdgcn_mfma_f32_16x16x32_bf16(qh[c], kfh, sacc[sub], 0, 0, 0);
                sacc[sub] = __builtin_amdgcn_mfma_f32_16x16x32_bf16(qh[c], kfl, sacc[sub], 0, 0, 0);
                sacc[sub] = __builtin_amdgcn_mfma_f32_16x16x32_bf16(ql[c], kfh, sacc[sub], 0, 0, 0);
            }
        }

        // ---- mask + online softmax (C-layout: row q=g*4+r, col k=lr) ----
        float p[2][4];
        float mt[4] = {-INFINITY, -INFINITY, -INFINITY, -INFINITY};
#pragma unroll
        for (int sub = 0; sub < 2; ++sub) {
            const int kg = k0 + sub * 16 + lr;
#pragma unroll
            for (int r = 0; r < 4; ++r) {
                const int qg = q0 + w * 16 + g * 4 + r;
                const float logit = (kg > qg) ? sacc[sub][r] * scale : -FLT_MAX;
                p[sub][r] = logit;
                mt[r] = fmaxf(mt[r], logit);
            }
        }
#pragma unroll
        for (int r = 0; r < 4; ++r) {
            mt[r] = fmaxf(mt[r], __shfl_xor(mt[r], 1));
            mt[r] = fmaxf(mt[r], __shfl_xor(mt[r], 2));
            mt[r] = fmaxf(mt[r], __shfl_xor(mt[r], 4));
            mt[r] = fmaxf(mt[r], __shfl_xor(mt[r], 8));
        }
        float corr[4], rsum[4];
#pragma unroll
        for (int r = 0; r < 4; ++r) {
            const float mn = fmaxf(m[r], mt[r]);
            corr[r] = __expf(m[r] - mn);
            m[r] = mn;
            p[0][r] = __expf(p[0][r] - mn);
            p[1][r] = __expf(p[1][r] - mn);
            rsum[r] = p[0][r] + p[1][r];
            rsum[r] += __shfl_xor(rsum[r], 1);
            rsum[r] += __shfl_xor(rsum[r], 2);
            rsum[r] += __shfl_xor(rsum[r], 4);
            rsum[r] += __shfl_xor(rsum[r], 8);
            l[r] = l[r] * corr[r] + rsum[r];
        }
#pragma unroll
        for (int s2 = 0; s2 < 8; ++s2)
#pragma unroll
            for (int r = 0; r < 4; ++r) oacc[s2][r] *= corr[r];

        // ---- P -> LDS bf16 hi/lo (per-wave region) ----
#pragma unroll
        for (int sub = 0; sub < 2; ++sub)
#pragma unroll
            for (int r = 0; r < 4; ++r) {
                short hh, ll;
                split1(p[sub][r], hh, ll);
                Ph[w][g * 4 + r][sub * 16 + lr] = hh;
                Pl[w][g * 4 + r][sub * 16 + lr] = ll;
            }
        __syncthreads();   // P visible; also paces waves before next stage

        // ---- PV: A=P[16][32], B=VT; 8 d-subtiles x 3 terms ----
        const s16x8 pfh = *reinterpret_cast<const s16x8*>(&Ph[w][lr][g * 8]);
        const s16x8 pfl = *reinterpret_cast<const s16x8*>(&Pl[w][lr][g * 8]);
#pragma unroll
        for (int s2 = 0; s2 < 8; ++s2) {
            const s16x8 vfh = *reinterpret_cast<const s16x8*>(&VTh[s2 * 16 + lr][g * 8]);
            const s16x8 vfl = *reinterpret_cast<const s16x8*>(&VTl[s2 * 16 + lr][g * 8]);
            oacc[s2] = __builtin_amdgcn_mfma_f32_16x16x32_bf16(pfh, vfh, oacc[s2], 0, 0, 0);
            oacc[s2] = __builtin_amdgcn_mfma_f32_16x16x32_bf16(pfh, vfl, oacc[s2], 0, 0, 0);
            oacc[s2] = __builtin_amdgcn_mfma_f32_16x16x32_bf16(pfl, vfh, oacc[s2], 0, 0, 0);
        }
    }

    // ---- epilogue: O[q][d] / l[q] ----
    float inv[4];
#pragma unroll
    for (int r = 0; r < 4; ++r) inv[r] = 1.0f / l[r];
#pragma unroll
    for (int s2 = 0; s2 < 8; ++s2)
#pragma unroll
        for (int r = 0; r < 4; ++r)
            Ob[(size_t)(q0 + w * 16 + g * 4 + r) * DIM + s2 * 16 + lr] = oacc[s2][r] * inv[r];
}

// ---------------------------------------------------------------------------
// attn_f32 (fallback, R6-verified)
// ---------------------------------------------------------------------------
constexpr int KT = 32;

__global__ __launch_bounds__(256, 2) void attn_f32(const float* __restrict__ Q,
                                                   const float* __restrict__ Kp,
                                                   const float* __restrict__ Vp,
                                                   float* __restrict__ Op) {
    __shared__ float Ks[KT][HD];
    __shared__ float Vs[KT][HD];
    __shared__ float P[QT][KT];

    const int t = threadIdx.x;
    const int j = t & 7;
    const int rs = t >> 3;
    const int qRank = blockIdx.x >> 5;
    const int bh = blockIdx.x & 31;
    const int h = bh & 15;
    const int b = bh >> 4;
    const int qi = (qRank == 0) ? 31 : qRank - 1;
    const int q0 = qi * QT;
    const int sw = (j & 6) << 1;
    const float scale = 0.08838834764831845f;

    const size_t base = ((size_t)b * SEQ) * DIM + (size_t)h * HD;
    const float* Qb = Q + base;
    const float* Kb = Kp + base;
    const float* Vb = Vp + base;
    float* Ob = Op + base;

    float qf[2][16];
#pragma unroll
    for (int ri = 0; ri < 2; ++ri) {
        const float* src = Qb + (size_t)(q0 + rs + 32 * ri) * DIM + j * 16;
#pragma unroll
        for (int i = 0; i < 16; i += 4)
            *reinterpret_cast<float4*>(&qf[ri][i]) = *reinterpret_cast<const float4*>(src + i);
    }

    float m[2], l[2], o[2][16];
#pragma unroll
    for (int ri = 0; ri < 2; ++ri) {
        m[ri] = -INFINITY;
        l[ri] = 0.f;
#pragma unroll
        for (int i = 0; i < 16; ++i) o[ri][i] = 0.f;
    }

    const int ktStart = (qi == SEQ / QT - 1) ? 0 : (q0 + 1) / KT;

    for (int kt = ktStart; kt < SEQ / KT; ++kt) {
        const int k0 = kt * KT;
#pragma unroll
        for (int ii = 0; ii < 4; ++ii) {
            const int id = ii * 256 + t;
            const int kr = id >> 5;
            const int c4 = id & 31;
            const int pc = (c4 * 4) ^ ((c4 & 24) >> 1);
            *reinterpret_cast<float4*>(&Ks[kr][pc]) =
                *reinterpret_cast<const float4*>(Kb + (size_t)(k0 + kr) * DIM + c4 * 4);
            *reinterpret_cast<float4*>(&Vs[kr][pc]) =
                *reinterpret_cast<const float4*>(Vb + (size_t)(k0 + kr) * DIM + c4 * 4);
        }
        __syncthreads();

        float mt[2] = {-INFINITY, -INFINITY};
#pragma unroll 4
        for (int kk = 0; kk < KT; ++kk) {
            float kf[16];
#pragma unroll
            for (int i = 0; i < 4; ++i)
                *reinterpret_cast<float4*>(&kf[i * 4]) =
                    *reinterpret_cast<const float4*>(&Ks[kk][j * 16 + ((i * 4) ^ sw)]);
            const int kg = k0 + kk;
#pragma unroll
            for (int ri = 0; ri < 2; ++ri) {
                float s = 0.f;
#pragma unroll
                for (int i = 0; i < 16; ++i) s = fmaf(qf[ri][i], kf[i], s);
                s += __shfl_xor(s, 1);
                s += __shfl_xor(s, 2);
                s += __shfl_xor(s, 4);
                const int row = rs + 32 * ri;
                const int qg = q0 + row;
                const float logit = (kg > qg) ? s * scale : -FLT_MAX;
                mt[ri] = fmaxf(mt[ri], logit);
                if (j == 0) P[row][kk ^ (rs & 7)] = logit;
            }
        }
        __syncthreads();

#pragma unroll
        for (int ri = 0; ri < 2; ++ri) {
            const float mn = fmaxf(m[ri], mt[ri]);
            const float corr = __expf(m[ri] - mn);
            m[ri] = mn;
            l[ri] *= corr;
#pragma unroll
            for (int i = 0; i < 16; ++i) o[ri][i] *= corr;
        }

#pragma unroll 4
        for (int kk = 0; kk < KT; ++kk) {
            float vf[16];
#pragma unroll
            for (int i = 0; i < 4; ++i)
                *reinterpret_cast<float4*>(&vf[i * 4]) =
                    *reinterpret_cast<const float4*>(&Vs[kk][j * 16 + ((i * 4) ^ sw)]);
#pragma unroll
            for (int ri = 0; ri < 2; ++ri) {
                const float p = __expf(P[rs + 32 * ri][kk ^ (rs & 7)] - m[ri]);
                l[ri] += p;
#pragma unroll
                for (int i = 0; i < 16; ++i) o[ri][i] = fmaf(p, vf[i], o[ri][i]);
            }
        }
        __syncthreads();
    }

#pragma unroll
    for (int ri = 0; ri < 2; ++ri) {
        const float inv = 1.0f / l[ri];
        float* dst = Ob + (size_t)(q0 + rs + 32 * ri) * DIM + j * 16;
#pragma unroll
        for (int i = 0; i < 16; i += 4) {
            float4 v4;
            v4.x = o[ri][i + 0] * inv;
            v4.y = o[ri][i + 1] * inv;
            v4.z = o[ri][i + 2] * inv;
            v4.w = o[ri][i + 3] * inv;
            *reinterpret_cast<float4*>(dst + i) = v4;
        }
    }
}

// ---------------------------------------------------------------------------
extern "C" void kernel_launch(void* const* d_in, const int* in_sizes, int n_in,
                              void* d_out, int out_size, void* d_ws, size_t ws_size,
                              hipStream_t stream) {
    const float* x  = (const float*)d_in[0];
    const float* Wq = (const float*)d_in[1];
    const float* Wk = (const float*)d_in[2];
    const float* Wv = (const float*)d_in[3];
    const float* Wo = (const float*)d_in[4];
    float* out = (float*)d_out;

    char* ws = (char*)d_ws;
    float* Qw = (float*)(ws);
    float* Kw = (float*)(ws + 33554432);
    float* Vw = (float*)(ws + 67108864);
    float* Aw = (float*)(ws + 100663296);

    const dim3 blk(256);
    const dim3 agrid((SEQ / QT) * HEADS * BATCH);  // 1024
    const size_t NEED = 184549376ull;

    if (ws_size >= NEED) {
        unsigned short* xh  = (unsigned short*)(ws + 134217728);
        unsigned short* xl  = (unsigned short*)(ws + 150994944);
        unsigned short* wth = (unsigned short*)(ws + 167772160);
        unsigned short* wtl = (unsigned short*)(ws + 176160768);

        const dim3 cgrid(4096);
        const dim3 tgrid(DIM / 32, DIM / 32);
        const dim3 ggrid(DIM / 128, MROWS / 128);

        conv_split<<<cgrid, blk, 0, stream>>>(x, xh, xl);

        convT_split<<<tgrid, blk, 0, stream>>>(Wq, wth, wtl);
        gemm_bf16x3<<<ggrid, blk, 0, stream>>>(xh, xl, wth, wtl, Qw, MROWS, DIM, DIM);
        convT_split<<<tgrid, blk, 0, stream>>>(Wk, wth, wtl);
        gemm_bf16x3<<<ggrid, blk, 0, stream>>>(xh, xl, wth, wtl, Kw, MROWS, DIM, DIM);
        convT_split<<<tgrid, blk, 0, stream>>>(Wv, wth, wtl);
        gemm_bf16x3<<<ggrid, blk, 0, stream>>>(xh, xl, wth, wtl, Vw, MROWS, DIM, DIM);

        attn_mfma<<<agrid, blk, 0, stream>>>(Qw, Kw, Vw, Aw);

        conv_split<<<cgrid, blk, 0, stream>>>(Aw, xh, xl);
        convT_split<<<tgrid, blk, 0, stream>>>(Wo, wth, wtl);
        gemm_bf16x3<<<ggrid, blk, 0, stream>>>(xh, xl, wth, wtl, out, MROWS, DIM, DIM);
    } else {
        const dim3 ggrid(DIM / 128, MROWS / 128);
        gemm_f32<<<ggrid, blk, 0, stream>>>(x, Wq, Qw, MROWS, DIM, DIM);
        gemm_f32<<<ggrid, blk, 0, stream>>>(x, Wk, Kw, MROWS, DIM, DIM);
        gemm_f32<<<ggrid, blk, 0, stream>>>(x, Wv, Vw, MROWS, DIM, DIM);
        attn_f32<<<agrid, blk, 0, stream>>>(Qw, Kw, Vw, Aw);
        gemm_f32<<<ggrid, blk, 0, stream>>>(Aw, Wo, out, MROWS, DIM, DIM);
    }
}